// Round 1
// baseline (120.097 us; speedup 1.0000x reference)
//
#include <hip/hip_runtime.h>

// Fused SSIM loss via MFMA separable blur (fp16 planes). B=32, C=1, 512x512.
// Blur = two banded matmuls, band A[m][k] = g[k-m-3] held in one fragment
// (the -3 absorbs the halo shift from -5 to -8 that makes staging float4-aligned).
// Tile 64x32, 4096 blocks, ~43KB LDS -> 3 blocks/CU.
// Only p,t staged in LDS (2 planes); s=p^2+t^2 and q=p*t fragments are built
// in-register with packed fp16 right before the vertical MFMA (blur is linear,
// squaring must precede the blur, but it needn't go through LDS).
// rawT XOR-swizzled (8B sub-chunks, 16/column) -> 2-way (free) read conflicts.
// Reduction: plain per-block partial store + tiny second kernel.
// (R8 lesson: same-address atomics + device fences cost ~200us.)
typedef _Float16 f16x2 __attribute__((ext_vector_type(2)));
typedef _Float16 f16x4 __attribute__((ext_vector_type(4)));
typedef _Float16 f16x8 __attribute__((ext_vector_type(8)));
typedef float    f32x4 __attribute__((ext_vector_type(4)));

#define NBLK 4096    // 32 images * 8 x-tiles * 16 y-tiles

__device__ __forceinline__ f16x2 pkrtz(float a, float b) {
    return __builtin_bit_cast(f16x2, __builtin_amdgcn_cvt_pkrtz(a, b));
}

__global__ __launch_bounds__(256, 3)
void ssim_fused(const float* __restrict__ pred,
                const float* __restrict__ targ,
                const float* __restrict__ win,
                float* __restrict__ partial)
{
    // rawT: [plane:2][x:80][y-cap:64 halfwords, 16 swizzled 8B sub-chunks] = 20 KiB
    // vbuf: [plane:4][y:32][x: stride 88] fp16 = 22 KiB
    __shared__ __align__(16) _Float16 rawT[2 * 80 * 64];
    __shared__ __align__(16) _Float16 vbuf[4 * 32 * 88];
    __shared__ float gw[16];
    __shared__ float wsum[4];

    const int tid  = threadIdx.x;
    const int lane = tid & 63;
    const int wv   = tid >> 6;
    const int bid  = blockIdx.x;
    const int b    = bid >> 7;        // 128 tiles per image
    const int rem  = bid & 127;
    const int ty   = rem >> 3;        // 0..15
    const int tx   = rem & 7;         // 0..7
    const int x0g  = tx * 64 - 8;     // -8 (not -5) => float4-aligned staging
    const int y0g  = ty * 32 - 8;

    // 1-D gaussian = row sums of the 2-D window (window sums to 1).
    if (tid < 11) {
        float s = 0.f;
        #pragma unroll
        for (int j = 0; j < 11; ++j) s += win[tid * 11 + j];
        gw[tid] = s;
    }

    const float* pb = pred + (size_t)b * (512 * 512);
    const float* tb = targ + (size_t)b * (512 * 512);
    const bool interior = (tx >= 1) & (tx <= 6) & (ty >= 1) & (ty <= 14);

    // ---- Stage raw^T p,t planes (fp16, pkrtz), zero-pad outside (SAME). ----
    // 240 threads: each owns one (x-quad, y-quad): 20 x-blocks of 4, 12 y-quads.
    // 8 aligned float4 loads/thread, then 4x4 in-register transpose to columns.
    // Swizzle: 8B sub-chunk sc' = (qy&8) | ((qy&7) ^ ((x>>1)&7)).
    if (tid < 240) {
        const int xi = tid % 20;
        const int qy = tid / 20;          // 0..11
        const int lx = xi * 4;
        const int gx = x0g + lx;          // multiple of 4 -> 16B aligned
        const int gy = y0g + qy * 4;
        float4 pr[4], tr[4];
        if (interior) {
            const float* pp = pb + (size_t)gy * 512 + gx;
            const float* tp = tb + (size_t)gy * 512 + gx;
            #pragma unroll
            for (int r = 0; r < 4; ++r) {
                pr[r] = *(const float4*)(pp + r * 512);
                tr[r] = *(const float4*)(tp + r * 512);
            }
        } else {
            const bool xin = (gx >= 0) & (gx + 3 < 512);
            #pragma unroll
            for (int r = 0; r < 4; ++r) {
                const int gyr = gy + r;
                const bool yok = (unsigned)gyr < 512u;
                if (yok && xin) {
                    pr[r] = *(const float4*)(pb + (size_t)gyr * 512 + gx);
                    tr[r] = *(const float4*)(tb + (size_t)gyr * 512 + gx);
                } else {
                    float4 pz = {0.f, 0.f, 0.f, 0.f};
                    float4 tz = {0.f, 0.f, 0.f, 0.f};
                    if (yok) {
                        #pragma unroll
                        for (int e = 0; e < 4; ++e) {
                            const int gxe = gx + e;
                            if ((unsigned)gxe < 512u) {
                                pz[e] = pb[(size_t)gyr * 512 + gxe];
                                tz[e] = tb[(size_t)gyr * 512 + gxe];
                            }
                        }
                    }
                    pr[r] = pz; tr[r] = tz;
                }
            }
        }
        #pragma unroll
        for (int e = 0; e < 4; ++e) {
            const int x  = lx + e;
            const int sw = (x >> 1) & 7;
            const int sc = (qy & 8) | ((qy & 7) ^ sw);
            _Float16* col = &rawT[x * 64 + sc * 4];
            union { f16x2 h2[2]; f16x4 v; } u;
            u.h2[0] = pkrtz(pr[0][e], pr[1][e]);
            u.h2[1] = pkrtz(pr[2][e], pr[3][e]);
            *(f16x4*)col = u.v;
            u.h2[0] = pkrtz(tr[0][e], tr[1][e]);
            u.h2[1] = pkrtz(tr[2][e], tr[3][e]);
            *(f16x4*)(col + 5120) = u.v;
        }
    }
    __syncthreads();

    // ---- Band fragment A[m][k] = g[k-m-3] (m=lane&15, k=quad*8+j). ----
    // Shared by both passes: staged halo starts at -8, band center offset 8 => d=k-m-3.
    const int mrow = lane & 15;
    const int quad = lane >> 4;
    f16x8 afr;
    #pragma unroll
    for (int j = 0; j < 8; ++j) {
        const int d = quad * 8 + j - mrow - 3;
        afr[j] = (d >= 0 && d < 11) ? (_Float16)gw[d] : (_Float16)0.f;
    }
    const f32x4 z4 = {0.f, 0.f, 0.f, 0.f};
    const int swr = mrow >> 1;           // (x>>1)&7 for x = 16c + mrow

    // ---- Pass 1 (vertical): wave wv owns output plane wv; 5 x-chunks x 2 y-halves.
    // V[m][x] = sum_k g[k-m-3] * raw[ys = h*16+k][x].
    // s/q fragments built from p,t fragments via packed fp16.
    #pragma unroll
    for (int c = 0; c < 5; ++c) {
        const int x = c * 16 + mrow;
        const _Float16* bp = &rawT[x * 64];
        #pragma unroll
        for (int h = 0; h < 2; ++h) {
            const int sc0 = h * 4 + 2 * quad;
            const int sc1 = sc0 + 1;
            const int o0  = (((sc0 & 8) | ((sc0 & 7) ^ swr))) << 2;
            const int o1  = (((sc1 & 8) | ((sc1 & 7) ^ swr))) << 2;
            union { f16x4 q[2]; f16x8 v; } pu, tu;
            if (wv != 1) {
                pu.q[0] = *(const f16x4*)&bp[o0];
                pu.q[1] = *(const f16x4*)&bp[o1];
            }
            if (wv != 0) {
                tu.q[0] = *(const f16x4*)&bp[5120 + o0];
                tu.q[1] = *(const f16x4*)&bp[5120 + o1];
            }
            f16x8 frag;
            if      (wv == 0) frag = pu.v;
            else if (wv == 1) frag = tu.v;
            else if (wv == 2) frag = pu.v * pu.v + tu.v * tu.v;   // v_pk_fma_f16
            else              frag = pu.v * tu.v;
            const f32x4 dv = __builtin_amdgcn_mfma_f32_16x16x32_f16(afr, frag, z4, 0, 0, 0);
            _Float16* vb = &vbuf[wv * 2816 + (h * 16 + quad * 4) * 88 + x];
            #pragma unroll
            for (int r = 0; r < 4; ++r)
                vb[r * 88] = (_Float16)dv[r];
        }
    }
    __syncthreads();

    // ---- Pass 2 (horizontal) + SSIM: wave wv owns x-tile X0 = 16*wv, both y-halves.
    float lsum = 0.f;
    {
        const int X0 = wv * 16;
        #pragma unroll
        for (int yh = 0; yh < 2; ++yh) {
            f32x4 dq[4];
            #pragma unroll
            for (int pl = 0; pl < 4; ++pl) {
                const f16x8 bv = *(const f16x8*)
                    &vbuf[pl * 2816 + (yh * 16 + mrow) * 88 + X0 + quad * 8];
                dq[pl] = __builtin_amdgcn_mfma_f32_16x16x32_f16(afr, bv, z4, 0, 0, 0);
            }
            #pragma unroll
            for (int r = 0; r < 4; ++r) {
                const float mp = dq[0][r], mt = dq[1][r];
                const float sv = dq[2][r], qv = dq[3][r];
                const float mp2 = mp * mp, mt2 = mt * mt, mpt = mp * mt;
                const float sig = fmaxf(sv - mp2 - mt2, 0.f);
                const float cv  = qv - mpt;
                const float num = (2.f * mpt + 1e-4f) * (2.f * cv + 9e-4f);
                const float den = (mp2 + mt2 + 1e-4f) * (sig + 9e-4f);
                lsum += num * __builtin_amdgcn_rcpf(den + 1e-8f);
            }
        }
    }

    // ---- Block reduce -> one plain float store per block. ----
    #pragma unroll
    for (int off = 32; off > 0; off >>= 1)
        lsum += __shfl_down(lsum, off, 64);
    if (lane == 0) wsum[wv] = lsum;
    __syncthreads();
    if (tid == 0)
        partial[bid] = wsum[0] + wsum[1] + wsum[2] + wsum[3];
}

__global__ __launch_bounds__(256)
void ssim_reduce(const float* __restrict__ partial, float* __restrict__ out)
{
    __shared__ double ws[4];
    double s = 0.0;
    const f32x4* p4 = (const f32x4*)partial;
    for (int i = threadIdx.x; i < NBLK / 4; i += 256) {
        const f32x4 v = p4[i];
        s += (double)v[0] + (double)v[1] + (double)v[2] + (double)v[3];
    }
    #pragma unroll
    for (int off = 32; off > 0; off >>= 1)
        s += __shfl_down(s, off, 64);
    if ((threadIdx.x & 63) == 0) ws[threadIdx.x >> 6] = s;
    __syncthreads();
    if (threadIdx.x == 0) {
        const double tot = ws[0] + ws[1] + ws[2] + ws[3];
        out[0] = (float)(1.0 - tot / 8388608.0);
    }
}

extern "C" void kernel_launch(void* const* d_in, const int* in_sizes, int n_in,
                              void* d_out, int out_size, void* d_ws, size_t ws_size,
                              hipStream_t stream)
{
    const float* pred = (const float*)d_in[0];
    const float* targ = (const float*)d_in[1];
    const float* win  = (const float*)d_in[2];
    float* out     = (float*)d_out;
    float* partial = (float*)d_ws;      // NBLK floats = 16 KiB scratch

    ssim_fused<<<NBLK, 256, 0, stream>>>(pred, targ, win, partial);
    ssim_reduce<<<1, 256, 0, stream>>>(partial, out);
}

// Round 2
// 108.472 us; speedup vs baseline: 1.1072x; 1.1072x over previous
//
#include <hip/hip_runtime.h>

// Fused SSIM loss via MFMA separable blur (fp16 planes). B=32, C=1, 512x512.
// Blur = two banded matmuls, band frag[m][k] = g[k-m-3] held in one fragment
// (the -3 absorbs the halo shift from -5 to -8 that makes staging float4-aligned).
// Tile 64x16, 8192 blocks, ~21.5KB LDS -> 7 blocks/CU (28 waves/CU).
//   (R1 lesson: 64x32 tile = 43.5KB LDS = 3 blocks/CU = latency-bound, 44us.
//    FETCH_SIZE is already at the unique-input ideal; occupancy is the lever.)
// Only p,t staged in LDS; s=p^2+t^2, q=p*t built in-register (packed fp16)
// right before the vertical MFMA (blur is linear; squaring precedes blur but
// needn't go through LDS).
// Pass-1 MFMA uses SWAPPED operands mfma(raw, band): A/B fragments share the
// same lane mapping, so the transposed output lands 4-consecutive-x per lane
// -> vbuf writes are packed ds_write_b64 instead of 4x scalar u16.
// rawT XOR-swizzled with f(x) = ((x>>1)^(x>>4))&7 -> spreads both the 4-quad
// x-residue classes and the read columns across all 8 sub-chunk slots.
// Reduction: plain per-block partial store + tiny second kernel.
// (R8 lesson: same-address atomics + device fences cost ~200us.)
typedef _Float16 f16x2 __attribute__((ext_vector_type(2)));
typedef _Float16 f16x4 __attribute__((ext_vector_type(4)));
typedef _Float16 f16x8 __attribute__((ext_vector_type(8)));
typedef float    f32x4 __attribute__((ext_vector_type(4)));

#define NBLK 8192    // 32 images * 8 x-tiles * 32 y-tiles

__device__ __forceinline__ f16x2 pkrtz(float a, float b) {
    return __builtin_bit_cast(f16x2, __builtin_amdgcn_cvt_pkrtz(a, b));
}

__global__ __launch_bounds__(256, 7)
void ssim_fused(const float* __restrict__ pred,
                const float* __restrict__ targ,
                const float* __restrict__ win,
                float* __restrict__ partial)
{
    // rawT: [plane:2][x:80][y:32 halfwords = 8 swizzled 8B sub-chunks] = 10 KiB
    // vbuf: [plane:4][y:16][x: stride 88] fp16 = 11 KiB
    __shared__ __align__(16) _Float16 rawT[2 * 80 * 32];
    __shared__ __align__(16) _Float16 vbuf[4 * 16 * 88];
    __shared__ float gw[16];
    __shared__ float wsum[4];

    const int tid  = threadIdx.x;
    const int lane = tid & 63;
    const int wv   = tid >> 6;
    const int bid  = blockIdx.x;
    const int b    = bid >> 8;        // 256 tiles per image
    const int rem  = bid & 255;
    const int ty   = rem >> 3;        // 0..31
    const int tx   = rem & 7;         // 0..7
    const int x0g  = tx * 64 - 8;     // -8 (not -5) => float4-aligned staging
    const int y0g  = ty * 16 - 8;

    // 1-D gaussian = row sums of the 2-D window (window sums to 1).
    if (tid < 11) {
        float s = 0.f;
        #pragma unroll
        for (int j = 0; j < 11; ++j) s += win[tid * 11 + j];
        gw[tid] = s;
    }

    const float* pb = pred + (size_t)b * (512 * 512);
    const float* tb = targ + (size_t)b * (512 * 512);
    const bool interior = (tx >= 1) & (tx <= 6) & (ty >= 1) & (ty <= 30);

    // ---- Stage raw^T p,t planes (fp16, pkrtz), zero-pad outside (SAME). ----
    // 160 threads: each owns one 4x4 patch: xi = x-quad (20), qy = y-quad (8).
    // 8 aligned float4 loads/thread, 4x4 in-register transpose to columns.
    // gx is a multiple of 4, so an x-quad is either fully in [0,512) or fully out.
    if (tid < 160) {
        const int xi = tid % 20;
        const int qy = tid / 20;          // 0..7
        const int lx = xi * 4;
        const int gx = x0g + lx;          // multiple of 4 -> 16B aligned
        const int gy = y0g + qy * 4;
        float4 pr[4], tr[4];
        if (interior) {
            const float* pp = pb + (size_t)gy * 512 + gx;
            const float* tp = tb + (size_t)gy * 512 + gx;
            #pragma unroll
            for (int r = 0; r < 4; ++r) {
                pr[r] = *(const float4*)(pp + r * 512);
                tr[r] = *(const float4*)(tp + r * 512);
            }
        } else {
            const bool xin = ((unsigned)gx <= 508u);
            #pragma unroll
            for (int r = 0; r < 4; ++r) {
                const int gyr = gy + r;
                if (xin && (unsigned)gyr < 512u) {
                    pr[r] = *(const float4*)(pb + (size_t)gyr * 512 + gx);
                    tr[r] = *(const float4*)(tb + (size_t)gyr * 512 + gx);
                } else {
                    pr[r] = float4{0.f, 0.f, 0.f, 0.f};
                    tr[r] = float4{0.f, 0.f, 0.f, 0.f};
                }
            }
        }
        #pragma unroll
        for (int e = 0; e < 4; ++e) {
            const int x  = lx + e;
            const int f  = ((x >> 1) ^ (x >> 4)) & 7;
            _Float16* col = &rawT[x * 32 + ((qy ^ f) << 2)];
            union { f16x2 h2[2]; f16x4 v; } u;
            u.h2[0] = pkrtz(pr[0][e], pr[1][e]);
            u.h2[1] = pkrtz(pr[2][e], pr[3][e]);
            *(f16x4*)col = u.v;
            u.h2[0] = pkrtz(tr[0][e], tr[1][e]);
            u.h2[1] = pkrtz(tr[2][e], tr[3][e]);
            *(f16x4*)(col + 2560) = u.v;
        }
    }
    __syncthreads();

    // ---- Band fragment frag[m][k] = g[k-m-3] (m=lane&15, k=quad*8+j). ----
    // Identical lane mapping as A-frag (m=lane&15) and B-frag (n=lane&15),
    // so the same registers serve both MFMA operand slots.
    const int mrow = lane & 15;
    const int quad = lane >> 4;
    f16x8 afr;
    #pragma unroll
    for (int j = 0; j < 8; ++j) {
        const int d = quad * 8 + j - mrow - 3;
        afr[j] = (d >= 0 && d < 11) ? (_Float16)gw[d] : (_Float16)0.f;
    }
    const f32x4 z4 = {0.f, 0.f, 0.f, 0.f};

    // ---- Pass 1 (vertical): wave wv owns plane wv; 5 x-chunks, K=32 rows. ----
    // SWAPPED operands: D = raw^T * band => lane (mrow,quad) holds
    // V[y=mrow][x = 16c + 4*quad + r], 4 consecutive x -> packed b64 store.
    #pragma unroll
    for (int c = 0; c < 5; ++c) {
        const int x = c * 16 + mrow;
        const int f = ((x >> 1) ^ (x >> 4)) & 7;
        const _Float16* bp = &rawT[x * 32];
        const int o0 = ((2 * quad    ) ^ f) << 2;
        const int o1 = ((2 * quad + 1) ^ f) << 2;
        union { f16x4 q[2]; f16x8 v; } pu, tu;
        if (wv != 1) {
            pu.q[0] = *(const f16x4*)&bp[o0];
            pu.q[1] = *(const f16x4*)&bp[o1];
        }
        if (wv != 0) {
            tu.q[0] = *(const f16x4*)&bp[2560 + o0];
            tu.q[1] = *(const f16x4*)&bp[2560 + o1];
        }
        f16x8 frag;
        if      (wv == 0) frag = pu.v;
        else if (wv == 1) frag = tu.v;
        else if (wv == 2) frag = pu.v * pu.v + tu.v * tu.v;   // v_pk_fma_f16
        else              frag = pu.v * tu.v;
        const f32x4 dv = __builtin_amdgcn_mfma_f32_16x16x32_f16(frag, afr, z4, 0, 0, 0);
        union { f16x2 h2[2]; f16x4 v; } o;
        o.h2[0] = pkrtz(dv[0], dv[1]);
        o.h2[1] = pkrtz(dv[2], dv[3]);
        *(f16x4*)&vbuf[wv * 1408 + mrow * 88 + c * 16 + quad * 4] = o.v;
    }
    __syncthreads();

    // ---- Pass 2 (horizontal) + SSIM: wave wv owns x-tile X0 = 16*wv. ----
    float lsum = 0.f;
    {
        const int X0 = wv * 16;
        f32x4 dq[4];
        #pragma unroll
        for (int pl = 0; pl < 4; ++pl) {
            const f16x8 bv = *(const f16x8*)&vbuf[pl * 1408 + mrow * 88 + X0 + quad * 8];
            dq[pl] = __builtin_amdgcn_mfma_f32_16x16x32_f16(afr, bv, z4, 0, 0, 0);
        }
        #pragma unroll
        for (int r = 0; r < 4; ++r) {
            const float mp = dq[0][r], mt = dq[1][r];
            const float sv = dq[2][r], qv = dq[3][r];
            const float mp2 = mp * mp, mt2 = mt * mt, mpt = mp * mt;
            const float sig = fmaxf(sv - mp2 - mt2, 0.f);
            const float cv  = qv - mpt;
            const float num = (2.f * mpt + 1e-4f) * (2.f * cv + 9e-4f);
            const float den = (mp2 + mt2 + 1e-4f) * (sig + 9e-4f);
            lsum += num * __builtin_amdgcn_rcpf(den + 1e-8f);
        }
    }

    // ---- Block reduce -> one plain float store per block. ----
    #pragma unroll
    for (int off = 32; off > 0; off >>= 1)
        lsum += __shfl_down(lsum, off, 64);
    if (lane == 0) wsum[wv] = lsum;
    __syncthreads();
    if (tid == 0)
        partial[bid] = wsum[0] + wsum[1] + wsum[2] + wsum[3];
}

__global__ __launch_bounds__(256)
void ssim_reduce(const float* __restrict__ partial, float* __restrict__ out)
{
    __shared__ double ws[4];
    double s = 0.0;
    const f32x4* p4 = (const f32x4*)partial;
    for (int i = threadIdx.x; i < NBLK / 4; i += 256) {
        const f32x4 v = p4[i];
        s += (double)v[0] + (double)v[1] + (double)v[2] + (double)v[3];
    }
    #pragma unroll
    for (int off = 32; off > 0; off >>= 1)
        s += __shfl_down(s, off, 64);
    if ((threadIdx.x & 63) == 0) ws[threadIdx.x >> 6] = s;
    __syncthreads();
    if (threadIdx.x == 0) {
        const double tot = ws[0] + ws[1] + ws[2] + ws[3];
        out[0] = (float)(1.0 - tot / 8388608.0);
    }
}

extern "C" void kernel_launch(void* const* d_in, const int* in_sizes, int n_in,
                              void* d_out, int out_size, void* d_ws, size_t ws_size,
                              hipStream_t stream)
{
    const float* pred = (const float*)d_in[0];
    const float* targ = (const float*)d_in[1];
    const float* win  = (const float*)d_in[2];
    float* out     = (float*)d_out;
    float* partial = (float*)d_ws;      // NBLK floats = 32 KiB scratch

    ssim_fused<<<NBLK, 256, 0, stream>>>(pred, targ, win, partial);
    ssim_reduce<<<1, 256, 0, stream>>>(partial, out);
}